// Round 1
// baseline (524.465 us; speedup 1.0000x reference)
//
#include <hip/hip_runtime.h>
#include <stddef.h>

// Correlation cost volume: out[b, di*9+dj, h, w] =
//   (1/C) * sum_c x1[b,c,h,w] * x2[b,c,h+di-4,w+dj-4]  (zero padded)
// B=4, C=256, H=96, W=192, ODIM=9, PAD=4.

#define NC   256
#define HH   96
#define WW   192
#define NB   4
#define TW   16          // tile width  (pixels per block, w)
#define TH   8           // tile height (pixels per block, h)
#define PADP 4
#define XR   (TH + 2*PADP)   // 16 rows staged
#define XC   (TW + 2*PADP)   // 24 cols staged
#define CC   8               // channels per LDS chunk
#define CPAD 12              // padded channel stride (floats): 48B = 12 banks

__global__ __launch_bounds__(128) void corr_kernel(
    const float* __restrict__ x1,
    const float* __restrict__ x2,
    float* __restrict__ out)
{
    // channel-contiguous x2 tile: [row][col][chan]; chan stride padded to 12
    // floats so 16-lane b128 phases land <=2-way on banks. Row slots padded
    // to 25 so row stride (25*48B = 300 banks ≡ 12 mod 32) shifts banks.
    __shared__ __align__(16) float x2t[XR][XC + 1][CPAD];  // 19200 B

    const int tid = threadIdx.x;
    const int tw  = tid & (TW - 1);   // 0..15
    const int th  = tid >> 4;         // 0..7
    const int w0  = blockIdx.x * TW;
    const int h0  = blockIdx.y * TH;
    const int b   = blockIdx.z;

    const int h = h0 + th;
    const int w = w0 + tw;

    float acc[81];
#pragma unroll
    for (int d = 0; d < 81; ++d) acc[d] = 0.0f;

    for (int c0 = 0; c0 < NC; c0 += CC) {
        __syncthreads();   // previous chunk's reads done before overwrite

        // ---- stage x2 tile: CC * XR * XC = 3072 elements, 24 per thread ----
#pragma unroll
        for (int k = 0; k < (CC * XR * XC) / 128; ++k) {
            int e   = tid + k * 128;
            int col = e % XC;          // fastest -> coalesced 24-wide rows
            int t   = e / XC;
            int r   = t % XR;
            int c   = t / XR;          // 0..7
            int gh  = h0 - PADP + r;
            int gw  = w0 - PADP + col;
            float v = 0.0f;
            if (gh >= 0 && gh < HH && gw >= 0 && gw < WW)
                v = x2[((size_t)((b * NC + c0 + c) * HH + gh)) * WW + gw];
            x2t[r][col][c] = v;
        }
        __syncthreads();

        // ---- x1 for this pixel: straight from global, coalesced, read once
        float a[CC];
#pragma unroll
        for (int c = 0; c < CC; ++c)
            a[c] = x1[((size_t)((b * NC + c0 + c) * HH + h)) * WW + w];

        // ---- 81 displacements, 8 channels each (2x ds_read_b128) ----
#pragma unroll
        for (int di = 0; di < 9; ++di) {
#pragma unroll
            for (int dj = 0; dj < 9; ++dj) {
                const float* p = &x2t[th + di][tw + dj][0];
                float4 v0 = *(const float4*)(p);
                float4 v1 = *(const float4*)(p + 4);
                float s = acc[di * 9 + dj];
                s += a[0] * v0.x;
                s += a[1] * v0.y;
                s += a[2] * v0.z;
                s += a[3] * v0.w;
                s += a[4] * v1.x;
                s += a[5] * v1.y;
                s += a[6] * v1.z;
                s += a[7] * v1.w;
                acc[di * 9 + dj] = s;
            }
        }
    }

    // ---- epilogue: mean over C, write 81 channels (coalesced in w) ----
    const float scale = 1.0f / (float)NC;
#pragma unroll
    for (int d = 0; d < 81; ++d) {
        out[((size_t)((b * 81 + d) * HH + h)) * WW + w] = acc[d] * scale;
    }
}

extern "C" void kernel_launch(void* const* d_in, const int* in_sizes, int n_in,
                              void* d_out, int out_size, void* d_ws, size_t ws_size,
                              hipStream_t stream) {
    const float* x1 = (const float*)d_in[0];
    const float* x2 = (const float*)d_in[1];
    float* out = (float*)d_out;

    dim3 grid(WW / TW, HH / TH, NB);   // 12 x 12 x 4 = 576 blocks
    corr_kernel<<<grid, 128, 0, stream>>>(x1, x2, out);
}

// Round 2
// 261.092 us; speedup vs baseline: 2.0087x; 2.0087x over previous
//
#include <hip/hip_runtime.h>
#include <stddef.h>

// Correlation cost volume via bf16 MFMA band-matmul.
// out[b, di*9+dj, h, w] = (1/256) * sum_c x1[b,c,h,w] * x2[b,c,h+di-4,w+dj-4]
// B=4, C=256, H=96, W=192.
//
// Per (b, h, di): P[m,n] = sum_c x1[c, w0+m] * x2[c, h+di-4, w0-4+n],
// m in [0,16), n in [0,24) -> out[di*9+dj][w0+m] = P[m, m+dj].
// Two v_mfma_f32_16x16x32_bf16 per (di, k-chunk) cover n in [0,32).
// Block: 512 thr = 8 waves, wave wv <-> h row h0+wv. x2 halo rows staged in LDS.

#define NB 4
#define NC 256
#define HH 96
#define WW 192
#define TW 16
#define TH 8
#define KC 32
#define NROWS 16   // TH + 8 halo rows

// Flat LDS layout for x2 tile (bf16): [row][kg=k/8][n][k%8]
//   k-innermost 8 shorts -> one bf16x8 frag = 1 ds_read_b128 (16B aligned)
//   KS (kg stride) = 264 shorts -> frag-read bank spread = uniform 8/bank (minimum)
//   RS (row stride) = 1096 shorts -> staging b64 writes spread ~4-way, not 16-way
#define KS 264
#define RS 1096
#define XBI(row, kg, n) ((row) * RS + (kg) * KS + (n) * 8)

typedef __attribute__((ext_vector_type(8))) short bf16x8;
typedef __attribute__((ext_vector_type(4))) float f32x4;

__device__ __forceinline__ unsigned short f2bf(float f) {
    union { float f; unsigned u; } c; c.f = f;
    unsigned r = c.u + 0x7FFFu + ((c.u >> 16) & 1u);   // round-to-nearest-even
    return (unsigned short)(r >> 16);
}

__global__ __launch_bounds__(512, 2) void corr_mfma(
    const float* __restrict__ x1, const float* __restrict__ x2,
    float* __restrict__ out)
{
    __shared__ union {
        unsigned short xb[NROWS * RS];     // 35072 B: x2 bf16 tile
        float band[TH][9][9][18];          // 46656 B: epilogue staging (m-pad 18)
    } lds;

    const int tid  = threadIdx.x;
    const int wv   = tid >> 6;        // wave 0..7 -> h row
    const int lane = tid & 63;
    const int col  = lane & 15;       // MFMA m/n 16-index
    const int q    = lane >> 4;       // MFMA k-quad
    const int w0   = blockIdx.x * TW;
    const int h0   = blockIdx.y * TH;
    const int b    = blockIdx.z;
    const int h    = h0 + wv;

    f32x4 acc[9][2];
#pragma unroll
    for (int di = 0; di < 9; ++di) {
        acc[di][0] = (f32x4)0.0f;
        acc[di][1] = (f32x4)0.0f;
    }

    for (int kc = 0; kc < NC; kc += KC) {
        if (kc) __syncthreads();   // protect LDS from previous chunk's readers

        // ---- stage x2: 16 rows x 24 n x 32 ch; 768 tasks of (4 float4 loads ->
        //      4x4 transpose -> 4 ds_write_b64). seg fastest => coalesced global.
#pragma unroll
        for (int t0 = 0; t0 < 2; ++t0) {
            int t = tid + t0 * 512;
            if (t < 768) {
                int seg = t % 6;            // 4-wide w segment, gw = w0-4+seg*4
                int row = (t / 6) & 15;     // x2 row = h0-4+row
                int cg  = t / 96;           // channel group of 4: c = kc+cg*4+i
                int gh  = h0 - 4 + row;
                int gw  = w0 - 4 + seg * 4;
                bool ok = (gh >= 0) & (gh < HH) & (gw >= 0) & (gw + 3 < WW);
                float vv[4][4];
#pragma unroll
                for (int i = 0; i < 4; ++i) {
                    float4 ld = make_float4(0.f, 0.f, 0.f, 0.f);
                    if (ok) {
                        size_t idx = ((size_t)((b * NC + kc + cg * 4 + i) * HH + gh)) * WW + gw;
                        ld = *(const float4*)&x2[idx];
                    }
                    vv[i][0] = ld.x; vv[i][1] = ld.y; vv[i][2] = ld.z; vv[i][3] = ld.w;
                }
                int kg = cg >> 1;
                int k0 = 4 * (cg & 1);
#pragma unroll
                for (int p = 0; p < 4; ++p) {
                    ushort4 pk;
                    pk.x = f2bf(vv[0][p]); pk.y = f2bf(vv[1][p]);
                    pk.z = f2bf(vv[2][p]); pk.w = f2bf(vv[3][p]);
                    *(ushort4*)&lds.xb[XBI(row, kg, seg * 4 + p) + k0] = pk;
                }
            }
        }
        __syncthreads();

        // ---- A fragment (x1) straight from global: read exactly once
        bf16x8 a;
#pragma unroll
        for (int j = 0; j < 8; ++j) {
            size_t idx = ((size_t)((b * NC + kc + q * 8 + j) * HH + h)) * WW + w0 + col;
            a[j] = (short)f2bf(x1[idx]);
        }

        // ---- 9 displacements x 2 n-halves
#pragma unroll
        for (int di = 0; di < 9; ++di) {
            int r = wv + di;   // LDS row for x2 row h+di-4
            bf16x8 b0 = *(const bf16x8*)&lds.xb[XBI(r, q, col)];
            bf16x8 b1 = *(const bf16x8*)&lds.xb[XBI(r, q, col + 16)];
            acc[di][0] = __builtin_amdgcn_mfma_f32_16x16x32_bf16(a, b0, acc[di][0], 0, 0, 0);
            acc[di][1] = __builtin_amdgcn_mfma_f32_16x16x32_bf16(a, b1, acc[di][1], 0, 0, 0);
        }
    }

    __syncthreads();   // all frag reads done before band overwrites xb

    // ---- band extraction: P[m, m+dj] -> band[wv][di][dj][m]
    // D layout: col = lane&15 (=n), row m = q*4 + reg.
#pragma unroll
    for (int di = 0; di < 9; ++di)
#pragma unroll
        for (int half = 0; half < 2; ++half)
#pragma unroll
            for (int r = 0; r < 4; ++r) {
                int m  = q * 4 + r;
                int dj = half * 16 + col - m;
                if (dj >= 0 && dj < 9)
                    lds.band[wv][di][dj][m] = acc[di][half][r];
            }
    __syncthreads();

    // ---- coalesced write-out: 81 channels x 16 w per (b, h)
    const float scale = 1.0f / 256.0f;
#pragma unroll
    for (int it = 0; it < 21; ++it) {
        int combo = it * 4 + q;           // (di*9+dj)
        if (combo < 81) {
            float v = lds.band[wv][combo / 9][combo % 9][col];
            out[((size_t)((b * 81 + combo) * HH + h)) * WW + w0 + col] = v * scale;
        }
    }
}

extern "C" void kernel_launch(void* const* d_in, const int* in_sizes, int n_in,
                              void* d_out, int out_size, void* d_ws, size_t ws_size,
                              hipStream_t stream) {
    const float* x1 = (const float*)d_in[0];
    const float* x2 = (const float*)d_in[1];
    float* out = (float*)d_out;

    dim3 grid(WW / TW, HH / TH, NB);   // 12 x 12 x 4 = 576 blocks, 512 thr (8 waves)
    corr_mfma<<<grid, 512, 0, stream>>>(x1, x2, out);
}

// Round 3
// 245.324 us; speedup vs baseline: 2.1378x; 1.0643x over previous
//
#include <hip/hip_runtime.h>
#include <stddef.h>

// Correlation cost volume via bf16 MFMA band-matmul, register-prefetch pipelined.
// out[b, di*9+dj, h, w] = (1/256) * sum_c x1[b,c,h,w] * x2[b,c,h+di-4,w+dj-4]
// B=4, C=256, H=96, W=192.
//
// R2 -> R3: R2 was HBM-latency-bound (365MB / 2.44TB/s = 149us; ~1 outstanding
// load/thread). R3 prefetches chunk k+1's x2+x1 into VGPRs during chunk k's
// MFMA compute (~65KB/block in flight), converting latency-bound -> BW-bound.

#define NB 4
#define NC 256
#define HH 96
#define WW 192
#define TW 16
#define TH 8
#define KC 32
#define NROWS 16   // TH + 8 halo rows

// Flat LDS bf16 layout for x2 tile: [row][kg=k/8][n][k%8] (k-innermost 8 ->
// one bf16x8 B-frag = 1 ds_read_b128). KS=264, RS=1096 stagger bank groups.
#define KS 264
#define RS 1096
#define XBI(row, kg, n) ((row) * RS + (kg) * KS + (n) * 8)

typedef __attribute__((ext_vector_type(8))) short bf16x8;
typedef __attribute__((ext_vector_type(4))) float f32x4;

__device__ __forceinline__ unsigned short f2bf(float f) {
    union { float f; unsigned u; } c; c.f = f;
    unsigned r = c.u + 0x7FFFu + ((c.u >> 16) & 1u);   // round-to-nearest-even
    return (unsigned short)(r >> 16);
}

__global__ __launch_bounds__(512, 1) void corr_mfma(
    const float* __restrict__ x1, const float* __restrict__ x2,
    float* __restrict__ out)
{
    __shared__ union {
        unsigned short xb[NROWS * RS];     // 35072 B: x2 bf16 tile
        float band[TH][9][9][18];          // 46656 B: epilogue staging
    } lds;

    const int tid  = threadIdx.x;
    const int wv   = tid >> 6;        // wave 0..7 -> h row
    const int lane = tid & 63;
    const int col  = lane & 15;       // MFMA m/n 16-index
    const int q    = lane >> 4;       // MFMA k-quad
    const int w0   = blockIdx.x * TW;
    const int h0   = blockIdx.y * TH;
    const int b    = blockIdx.z;
    const int h    = h0 + wv;

    f32x4 acc[9][2];
#pragma unroll
    for (int di = 0; di < 9; ++di) {
        acc[di][0] = (f32x4)0.0f;
        acc[di][1] = (f32x4)0.0f;
    }

    // Prefetch registers: 3 staging tasks x 2 float4 (x2), 8 floats (x1).
    float pf[24];
    float pa[8];

    // ---- task decode: 1536 tasks/chunk, 3/thread. task = (cp, row, seg):
    //      2 channels (cp*2, cp*2+1) x 4 w at one x2 row. seg fastest->coalesced.
#define STAGE_LOAD(kc_)                                                        \
    {                                                                          \
        const int kcv = (kc_);                                                 \
        _Pragma("unroll")                                                      \
        for (int k = 0; k < 3; ++k) {                                          \
            int t   = tid + k * 512;                                           \
            int seg = t % 6;                                                   \
            int row = (t / 6) & 15;                                            \
            int cp  = t / 96;                                                  \
            int gh  = h0 - 4 + row;                                            \
            int gw  = w0 - 4 + seg * 4;                                        \
            bool ok = (gh >= 0) & (gh < HH) & (gw >= 0) & (gw <= WW - 4);      \
            _Pragma("unroll")                                                  \
            for (int e = 0; e < 2; ++e) {                                      \
                float4 ld = make_float4(0.f, 0.f, 0.f, 0.f);                   \
                if (ok) {                                                      \
                    size_t idx = ((size_t)((b * NC + kcv + cp * 2 + e) * HH + gh)) * WW + gw; \
                    ld = *(const float4*)&x2[idx];                             \
                }                                                              \
                *(float4*)&pf[(k * 2 + e) * 4] = ld;                           \
            }                                                                  \
        }                                                                      \
    }

#define X1_LOAD(kc_)                                                           \
    {                                                                          \
        const int kcv = (kc_);                                                 \
        _Pragma("unroll")                                                      \
        for (int j = 0; j < 8; ++j) {                                          \
            size_t idx = ((size_t)((b * NC + kcv + q * 8 + j) * HH + h)) * WW + w0 + col; \
            pa[j] = x1[idx];                                                   \
        }                                                                      \
    }

    STAGE_LOAD(0);
    X1_LOAD(0);

    for (int ci = 0; ci < 8; ++ci) {
        // ---- convert + store prefetched x2 regs to LDS (waits vmcnt here)
#pragma unroll
        for (int k = 0; k < 3; ++k) {
            int t   = tid + k * 512;
            int seg = t % 6;
            int row = (t / 6) & 15;
            int cp  = t / 96;
            int kg  = cp >> 2;
            int k0  = (cp & 3) * 2;
#pragma unroll
            for (int p = 0; p < 4; ++p) {
                ushort2 v;
                v.x = f2bf(pf[(k * 2 + 0) * 4 + p]);
                v.y = f2bf(pf[(k * 2 + 1) * 4 + p]);
                *(ushort2*)&lds.xb[XBI(row, kg, seg * 4 + p) + k0] = v;
            }
        }
        __syncthreads();

        // ---- pack this chunk's A-frag from prefetched x1 regs
        bf16x8 a;
#pragma unroll
        for (int j = 0; j < 8; ++j) a[j] = (short)f2bf(pa[j]);

        // ---- issue NEXT chunk's global loads; they fly during the MFMA phase
        if (ci < 7) {
            STAGE_LOAD((ci + 1) * KC);
            X1_LOAD((ci + 1) * KC);
        }

        // ---- 9 displacements x 2 n-halves
#pragma unroll
        for (int di = 0; di < 9; ++di) {
            int r = wv + di;   // LDS row for x2 row h+di-4
            bf16x8 b0 = *(const bf16x8*)&lds.xb[XBI(r, q, col)];
            bf16x8 b1 = *(const bf16x8*)&lds.xb[XBI(r, q, col + 16)];
            acc[di][0] = __builtin_amdgcn_mfma_f32_16x16x32_bf16(a, b0, acc[di][0], 0, 0, 0);
            acc[di][1] = __builtin_amdgcn_mfma_f32_16x16x32_bf16(a, b1, acc[di][1], 0, 0, 0);
        }
        __syncthreads();   // frag reads done before next store (or band) overwrites
    }

    // ---- band extraction: P[m, m+dj] -> band[wv][di][dj][m]
    // D layout: col = lane&15 (=n), row m = q*4 + reg.
#pragma unroll
    for (int di = 0; di < 9; ++di)
#pragma unroll
        for (int half = 0; half < 2; ++half)
#pragma unroll
            for (int r = 0; r < 4; ++r) {
                int m  = q * 4 + r;
                int dj = half * 16 + col - m;
                if (dj >= 0 && dj < 9)
                    lds.band[wv][di][dj][m] = acc[di][half][r];
            }
    __syncthreads();

    // ---- coalesced write-out: 81 channels x 16 w per (b, h)
    const float scale = 1.0f / 256.0f;
#pragma unroll
    for (int it = 0; it < 21; ++it) {
        int combo = it * 4 + q;           // (di*9+dj)
        if (combo < 81) {
            float v = lds.band[wv][combo / 9][combo % 9][col];
            out[((size_t)((b * 81 + combo) * HH + h)) * WW + w0 + col] = v * scale;
        }
    }
}

extern "C" void kernel_launch(void* const* d_in, const int* in_sizes, int n_in,
                              void* d_out, int out_size, void* d_ws, size_t ws_size,
                              hipStream_t stream) {
    const float* x1 = (const float*)d_in[0];
    const float* x2 = (const float*)d_in[1];
    float* out = (float*)d_out;

    dim3 grid(WW / TW, HH / TH, NB);   // 12 x 12 x 4 = 576 blocks, 512 thr (8 waves)
    corr_mfma<<<grid, 512, 0, stream>>>(x1, x2, out);
}